// Round 7
// baseline (233.628 us; speedup 1.0000x reference)
//
#include <hip/hip_runtime.h>

#define DEV __device__ __forceinline__
#define KSIG (-1.442695041f)
#define KTANH (-2.885390082f)

typedef float f2 __attribute__((ext_vector_type(2)));

DEV float fexp2(float x) { return __builtin_amdgcn_exp2f(x); }
DEV float frcp(float x) { return __builtin_amdgcn_rcpf(x); }
DEV float bperm(int a, float x) {
  return __int_as_float(__builtin_amdgcn_ds_bpermute(a, __float_as_int(x)));
}
DEV f2 pkfma(f2 a, f2 b, f2 c) { return __builtin_elementwise_fma(a, b, c); }

// Lane u of a 5-lane group owns state index j=u and gate rows
// {u,5+u,10+u,15+u} (i,f,g,o). kexp folded into weights/bias: sigmoid rows
// scaled by KSIG, g-row by KTANH; act = rcp(1+exp2(acc)), tanh = 2*act-1.
struct CellP {
  f2 wx[4][2];
  f2 wh[4][2];
  float wx4[4], wh4[4];
  f2 b2[4];  // {bias, 0}
};

DEV void load_cellP(CellP& W, int u, const float* __restrict__ Wih,
                    const float* __restrict__ Whh,
                    const float* __restrict__ bih,
                    const float* __restrict__ bhh) {
#pragma unroll
  for (int rt = 0; rt < 4; ++rt) {  // 0=i 1=f 2=g 3=o
    int row = 5 * rt + u;
    float kx = (rt == 2) ? KTANH : KSIG;
    W.wx[rt][0] = (f2){kx * Wih[row * 5 + 0], kx * Wih[row * 5 + 1]};
    W.wx[rt][1] = (f2){kx * Wih[row * 5 + 2], kx * Wih[row * 5 + 3]};
    W.wx4[rt] = kx * Wih[row * 5 + 4];
    W.wh[rt][0] = (f2){kx * Whh[row * 5 + 0], kx * Whh[row * 5 + 1]};
    W.wh[rt][1] = (f2){kx * Whh[row * 5 + 2], kx * Whh[row * 5 + 3]};
    W.wh4[rt] = kx * Whh[row * 5 + 4];
    W.b2[rt] = (f2){kx * (bih[row] + bhh[row]), 0.f};
  }
}

// One cell timestep; returns this lane's own h_j(t). hAll: h(t-1) in, h(t) out.
DEV float stepP(const CellP& W, const f2 xp[2], float x4, float hAll[5],
                float& c, const int bp[5]) {
  f2 hp0 = (f2){hAll[0], hAll[1]};
  f2 hp1 = (f2){hAll[2], hAll[3]};
  float acc[4];
#pragma unroll
  for (int rt = 0; rt < 4; ++rt) {
    f2 a2 = pkfma(W.wx[rt][0], xp[0], W.b2[rt]);
    a2 = pkfma(W.wx[rt][1], xp[1], a2);
    a2 = pkfma(W.wh[rt][0], hp0, a2);
    a2 = pkfma(W.wh[rt][1], hp1, a2);
    float a = a2.x + a2.y;
    a = fmaf(W.wx4[rt], x4, a);
    acc[rt] = fmaf(W.wh4[rt], hAll[4], a);
  }
  float gi = frcp(1.f + fexp2(acc[0]));
  float gf = frcp(1.f + fexp2(acc[1]));
  float gg = fmaf(2.f, frcp(1.f + fexp2(acc[2])), -1.f);
  float go = frcp(1.f + fexp2(acc[3]));
  c = fmaf(gf, c, gi * gg);
  float th = fmaf(2.f, frcp(1.f + fexp2(KTANH * c)), -1.f);
  float h = go * th;
#pragma unroll
  for (int u2 = 0; u2 < 5; ++u2) hAll[u2] = bperm(bp[u2], h);
  return h;
}

// Block = 192 threads = 3 waves, 12 elements (5 lanes each; lanes 60..63
// idle). wave0: lstm1 (independent). wave1: lstm2a, publishes h2a(t) into
// sH[t&15]. wave2: lstm2b, runs 8 steps BEHIND, consuming slots written
// before the previous barrier. One __syncthreads per 8 timesteps (17 total).
// Ring safety: in outer iter it, wave1 writes slots (it*8..it*8+7)&15 and
// wave2 reads the other half; the barrier separates RAW and WAR reuse.
// FC stack fused at the end, task-split over all 192 lanes.
__global__ __launch_bounds__(192, 4) void rnn_ring_kernel(
    const float* __restrict__ x1, const float* __restrict__ x2,
    const float* __restrict__ Wih1, const float* __restrict__ Whh1,
    const float* __restrict__ bih1, const float* __restrict__ bhh1,
    const float* __restrict__ Wih2a, const float* __restrict__ Whh2a,
    const float* __restrict__ bih2a, const float* __restrict__ bhh2a,
    const float* __restrict__ Wih2b, const float* __restrict__ Whh2b,
    const float* __restrict__ bih2b, const float* __restrict__ bhh2b,
    const float* __restrict__ W1, const float* __restrict__ b1,
    const float* __restrict__ W2, const float* __restrict__ b2,
    const float* __restrict__ W3, const float* __restrict__ b3,
    const float* __restrict__ W4, const float* __restrict__ b4,
    const float* __restrict__ W5, const float* __restrict__ b5,
    float* __restrict__ out, int B) {
  __shared__ float sH[16][64];  // h2a ring: [slot][g*5+u]; words 60..63 junk
  __shared__ float sIn[12][20];
  __shared__ float sA[12][32];
  __shared__ float sB[12][32];

  const int tid = threadIdx.x;
  const int w = tid >> 6;  // wave role: 0=lstm1 1=lstm2a 2=lstm2b
  const int l = tid & 63;
  const int g = l / 5;
  const int u = l - 5 * g;
  const bool act = (g < 12);
  const int el = act ? g : 11;
  const int eg = blockIdx.x * 12 + el;
  const int egc = (eg < B) ? eg : (B - 1);

  int bp[5];
#pragma unroll
  for (int u2 = 0; u2 < 5; ++u2) bp[u2] = (5 * g + u2) * 4;

  float hAll[5];
  float c = 0.f, hOwn = 0.f;
#pragma unroll
  for (int k = 0; k < 5; ++k) hAll[k] = 0.f;

  if (w == 0) {  // ---------------- lstm1 ----------------
    CellP W;
    load_cellP(W, u, Wih1, Whh1, bih1, bhh1);
    const float* px = x1 + (size_t)egc * 640;
    f2 xp[2] = {(f2){px[0], px[1]}, (f2){px[2], px[3]}};
    float x4 = px[4];
    for (int it = 0; it < 16; ++it) {
#pragma unroll
      for (int k = 0; k < 8; ++k) {
        const int t = it * 8 + k;
        const int tn = (t < 127) ? t + 1 : 127;
        f2 n0 = (f2){px[tn * 5 + 0], px[tn * 5 + 1]};
        f2 n1 = (f2){px[tn * 5 + 2], px[tn * 5 + 3]};
        float n4 = px[tn * 5 + 4];
        hOwn = stepP(W, xp, x4, hAll, c, bp);
        xp[0] = n0;
        xp[1] = n1;
        x4 = n4;
      }
      __syncthreads();
    }
    if (act) {
      sIn[el][u] = x1[(size_t)egc * 640 + 635 + u];  // x1 last
      sIn[el][10 + u] = hOwn;                        // out1 = h1(127)
    }
  } else if (w == 1) {  // ---------------- lstm2a ----------------
    CellP W;
    load_cellP(W, u, Wih2a, Whh2a, bih2a, bhh2a);
    const float* px = x2 + (size_t)egc * 640;
    f2 xp[2] = {(f2){px[0], px[1]}, (f2){px[2], px[3]}};
    float x4 = px[4];
    for (int it = 0; it < 16; ++it) {
#pragma unroll
      for (int k = 0; k < 8; ++k) {
        const int t = it * 8 + k;
        const int tn = (t < 127) ? t + 1 : 127;
        f2 n0 = (f2){px[tn * 5 + 0], px[tn * 5 + 1]};
        f2 n1 = (f2){px[tn * 5 + 2], px[tn * 5 + 3]};
        float n4 = px[tn * 5 + 4];
        hOwn = stepP(W, xp, x4, hAll, c, bp);
        sH[t & 15][l] = hOwn;  // publish h2a(t); lanes 60..63 write junk words
        xp[0] = n0;
        xp[1] = n1;
        x4 = n4;
      }
      __syncthreads();
    }
    if (act) sIn[el][5 + u] = x2[(size_t)egc * 640 + 635 + u];  // x2 last
  } else {  // ---------------- lstm2b (8 steps behind) ----------------
    CellP W;
    load_cellP(W, u, Wih2b, Whh2b, bih2b, bhh2b);
    const int sbase = g * 5;
    for (int it = 0; it < 16; ++it) {
      if (it > 0) {
#pragma unroll
        for (int k = 0; k < 8; ++k) {
          const int t = (it - 1) * 8 + k;
          const float* s = &sH[t & 15][sbase];
          f2 xin[2] = {(f2){s[0], s[1]}, (f2){s[2], s[3]}};
          hOwn = stepP(W, xin, s[4], hAll, c, bp);
        }
      }
      __syncthreads();
    }
#pragma unroll
    for (int k = 0; k < 8; ++k) {  // tail: steps 120..127
      const int t = 120 + k;
      const float* s = &sH[t & 15][sbase];
      f2 xin[2] = {(f2){s[0], s[1]}, (f2){s[2], s[3]}};
      hOwn = stepP(W, xin, s[4], hAll, c, bp);
    }
    if (act) sIn[el][15 + u] = hOwn;  // out2 = h2b(127)
  }
  __syncthreads();

  // FC stack: task-split over 192 lanes; weights from global (L1-cached).
  for (int task = tid; task < 12 * 32; task += 192) {
    int e = task >> 5, n = task & 31;
    float acc = b1[n];
#pragma unroll
    for (int k = 0; k < 20; ++k) acc = fmaf(W1[n * 20 + k], sIn[e][k], acc);
    sA[e][n] = fmaxf(acc, 0.f);
  }
  __syncthreads();
  for (int task = tid; task < 12 * 32; task += 192) {
    int e = task >> 5, n = task & 31;
    float acc = b2[n];
#pragma unroll
    for (int k = 0; k < 32; ++k) acc = fmaf(W2[n * 32 + k], sA[e][k], acc);
    sB[e][n] = fmaxf(acc, 0.f);
  }
  __syncthreads();
  {  // 12*16 = 192 tasks, exactly one per lane
    int e = tid >> 4, n = tid & 15;
    float acc = b3[n];
#pragma unroll
    for (int k = 0; k < 32; ++k) acc = fmaf(W3[n * 32 + k], sB[e][k], acc);
    sA[e][n] = fmaxf(acc, 0.f);  // reuse sA cols 0..15
  }
  __syncthreads();
  {
    int e = tid >> 4, n = tid & 15;
    float acc = b4[n];
#pragma unroll
    for (int k = 0; k < 16; ++k) acc = fmaf(W4[n * 16 + k], sA[e][k], acc);
    sB[e][n] = fmaxf(acc, 0.f);
  }
  __syncthreads();
  if (tid < 60) {  // 12 elems x 5 outputs
    int e = tid / 5, n = tid - 5 * (tid / 5);
    float acc = b5[n];
#pragma unroll
    for (int k = 0; k < 16; ++k) acc = fmaf(W5[n * 16 + k], sB[e][k], acc);
    int ego = blockIdx.x * 12 + e;
    if (ego < B) out[(size_t)ego * 5 + n] = acc;
  }
}

extern "C" void kernel_launch(void* const* d_in, const int* in_sizes, int n_in,
                              void* d_out, int out_size, void* d_ws,
                              size_t ws_size, hipStream_t stream) {
  const float* x1 = (const float*)d_in[0];
  const float* x2 = (const float*)d_in[1];
  const float* Wih1 = (const float*)d_in[2];
  const float* Whh1 = (const float*)d_in[3];
  const float* bih1 = (const float*)d_in[4];
  const float* bhh1 = (const float*)d_in[5];
  const float* Wih2a = (const float*)d_in[6];
  const float* Whh2a = (const float*)d_in[7];
  const float* bih2a = (const float*)d_in[8];
  const float* bhh2a = (const float*)d_in[9];
  const float* Wih2b = (const float*)d_in[10];
  const float* Whh2b = (const float*)d_in[11];
  const float* bih2b = (const float*)d_in[12];
  const float* bhh2b = (const float*)d_in[13];
  const float* W1 = (const float*)d_in[14];
  const float* b1 = (const float*)d_in[15];
  const float* W2 = (const float*)d_in[16];
  const float* b2 = (const float*)d_in[17];
  const float* W3 = (const float*)d_in[18];
  const float* b3 = (const float*)d_in[19];
  const float* W4 = (const float*)d_in[20];
  const float* b4 = (const float*)d_in[21];
  const float* W5 = (const float*)d_in[22];
  const float* b5 = (const float*)d_in[23];

  int B = in_sizes[0] / 640;  // [B,128,5]
  int nB = (B + 11) / 12;     // 12 elements per block

  rnn_ring_kernel<<<nB, 192, 0, stream>>>(
      x1, x2, Wih1, Whh1, bih1, bhh1, Wih2a, Whh2a, bih2a, bhh2a, Wih2b, Whh2b,
      bih2b, bhh2b, W1, b1, W2, b2, W3, b3, W4, b4, W5, b5, (float*)d_out, B);
}